// Round 10
// baseline (155.833 us; speedup 1.0000x reference)
//
#include <hip/hip_runtime.h>

#define FDIM   251
#define NFILT  80
#define KPAD   256        // K padded to 8 chunks of 32 (zeros past 250)
#define T_IN   64000
#define T_OUT  63750      // 64000 - 251 + 1
#define NCHUNK 1024       // output positions per block; wave owns contiguous 256
#define NFT    5          // filter tiles (16 filters each)
#define CPYLEN 648        // dwords per shifted copy; 648 % 32 == 8 -> bank stagger
#define XSTOT  (8 * CPYLEN)

typedef short bf16x8 __attribute__((ext_vector_type(8)));
typedef float f32x4  __attribute__((ext_vector_type(4)));

__device__ __forceinline__ unsigned short f2bf(float f) {
  unsigned int u = __float_as_uint(f);
  unsigned int r = (u + 0x7fffu + ((u >> 16) & 1u)) >> 16;   // RNE
  return (unsigned short)r;
}
__device__ __forceinline__ unsigned int packbf(float a, float b) {
  return (unsigned int)f2bf(a) | ((unsigned int)f2bf(b) << 16);
}

// ---------------------------------------------------------------------------
// Filter construction (validated rounds 1-9). Emits bf16 W[80][256].
// ---------------------------------------------------------------------------
__device__ __forceinline__ void norm_pm1_shared(float* a, float* scratch, int tid) {
  float v  = (tid < FDIM) ? a[tid] : 0.f;
  float mn = (tid < FDIM) ? v : 1e30f;
  float mx = (tid < FDIM) ? v : -1e30f;
  #pragma unroll
  for (int o = 32; o > 0; o >>= 1) {
    mn = fminf(mn, __shfl_down(mn, o));
    mx = fmaxf(mx, __shfl_down(mx, o));
  }
  const int wid = tid >> 6;
  if ((tid & 63) == 0) { scratch[wid] = mn; scratch[4 + wid] = mx; }
  __syncthreads();
  if (tid == 0) {
    scratch[0] = fminf(fminf(scratch[0], scratch[1]), fminf(scratch[2], scratch[3]));
    scratch[4] = fmaxf(fmaxf(scratch[4], scratch[5]), fmaxf(scratch[6], scratch[7]));
  }
  __syncthreads();
  const float gmn = scratch[0], gmx = scratch[4];
  const float nv = 2.f * (v - gmn) / (gmx - gmn + 1e-6f) - 1.f;
  __syncthreads();
  float s = (tid < FDIM) ? nv : 0.f;
  #pragma unroll
  for (int o = 32; o > 0; o >>= 1) s += __shfl_down(s, o);
  if ((tid & 63) == 0) scratch[wid] = s;
  __syncthreads();
  if (tid == 0) scratch[0] = (scratch[0] + scratch[1] + scratch[2] + scratch[3]) / 251.f;
  __syncthreads();
  const float mean = scratch[0];
  if (tid < FDIM) a[tid] = nv - mean;
  __syncthreads();
}

__global__ __launch_bounds__(256) void build_filters_kernel(
    const float* __restrict__ nf1, const float* __restrict__ nf2,
    const float* __restrict__ nf3, const float* __restrict__ nf4,
    const float* __restrict__ amp1, const float* __restrict__ amp2,
    unsigned short* __restrict__ Wbf) {
  __shared__ float ir1[FDIM], ir2[FDIM], casc[FDIM];
  __shared__ float scratch[8];
  const int f = blockIdx.x, tid = threadIdx.x;
  const float FS  = 16000.f;
  const float MF  = 50.f / 16000.f;
  const float PIF = 3.14159265358979323846f;
  const float TPI = 6.28318530717958647692f;

  const float f1 = fminf(fmaxf(fabsf(nf1[f]) + MF, 0.f), 0.5f);
  const float f2 = fminf(fmaxf(f1 + fabsf(nf2[f] - f1) + MF, 0.f), 0.5f);
  const float f3 = fminf(fmaxf(fabsf(nf3[f]) + MF, 0.f), 0.5f);
  const float f4 = fminf(fmaxf(f3 + fabsf(nf4[f] - f3) + MF, 0.f), 0.5f);
  const float a1 = fabsf(amp1[f]);
  const float a2 = fabsf(amp2[f]);

  if (tid < FDIM) {
    const float t = (float)(tid + 1) / FS;
    {
      const float fcs = 0.5f * (f1 + f2) * FS, bws = (f2 - f1) * FS;
      const float pb = PIF * bws;
      ir1[tid] = a1 * expf(-2.f * pb * pb * (t * t)) * cosf(TPI * fcs * t);
    }
    {
      const float fcs = 0.5f * (f3 + f4) * FS, bws = (f4 - f3) * FS;
      const float pb = PIF * bws;
      ir2[tid] = a2 * expf(-2.f * pb * pb * (t * t)) * cosf(TPI * fcs * t);
    }
  }
  __syncthreads();
  norm_pm1_shared(ir1, scratch, tid);
  norm_pm1_shared(ir2, scratch, tid);

  if (tid < FDIM) {
    const int i = tid;
    const int plo = (i - 125 > 0) ? (i - 125) : 0;
    const int phi = (i + 125 < 250) ? (i + 125) : 250;
    float s = 0.f;
    for (int p = plo; p <= phi; ++p) s += ir1[p] * ir2[p + 125 - i];
    casc[i] = s;
  }
  __syncthreads();
  norm_pm1_shared(casc, scratch, tid);

  if (tid < KPAD) {
    float v = 0.f;
    if (tid < FDIM) {
      const float win = 0.54f - 0.46f * cosf(TPI * ((float)tid / 250.f));
      v = casc[tid] * win;
    }
    Wbf[(size_t)f * KPAD + tid] = f2bf(v);
  }
}

// ---------------------------------------------------------------------------
// Implicit-GEMM conv: EXACT round-7 structure (best so far, 59.7 us) with
// ONE change: nontemporal streaming stores. Theory: 163 MB of dirty output
// churning the 4MB-per-XCD L2 randomizes the HBM write stream (eviction
// order != issue order) -> page-activation per 64-128B granule -> ~half-rate
// writes that serialize against the 25-us LDS-pipe phase. nt stores bypass
// allocation so the write stream reaches HBM near issue order (sequential
// per row, interleaved with compute).
// ---------------------------------------------------------------------------
__global__ __launch_bounds__(256, 4) void conv_mfma_kernel(
    const float* __restrict__ xin, const unsigned short* __restrict__ Wbf,
    float* __restrict__ outp) {
  __shared__ __align__(16) unsigned int xs[XSTOT];
  const int tid = threadIdx.x;
  const int n0  = blockIdx.x * NCHUNK;
  const int ft  = blockIdx.y;
  const int b   = blockIdx.z;
  const int l   = tid & 63, w = tid >> 6;
  const int m   = l & 15, h = l >> 4;

  // ---- stage x as 8 shifted bf16-pair copies: C_j[i] = (x[2i+j], x[2i+j+1]) ----
  const float* xg = xin + (size_t)b * T_IN;
  for (int i = tid; i < CPYLEN - 4; i += 256) {
    float e[10];
    #pragma unroll
    for (int q = 0; q < 10; ++q) {
      const int g = n0 + 2 * i + q;
      e[q] = (g < T_IN) ? xg[g] : 0.f;
    }
    #pragma unroll
    for (int j = 0; j < 8; ++j)
      xs[j * CPYLEN + i] = packbf(e[j], e[j + 1]);
  }

  // ---- W fragments (A-operand) for this 16-filter tile: row = m ----
  const short* Wp = (const short*)Wbf;
  bf16x8 afr[8];
  #pragma unroll
  for (int c = 0; c < 8; ++c)
    afr[c] = *(const bf16x8*)(Wp + (ft * 16 + m) * KPAD + c * 32 + h * 8);

  __syncthreads();

  // lane-constant fragment addressing (validated r4-r9):
  // tile j, chunk c -> copy m&7, 16B-unit index tw0/8 + 2j + lane_q + 4c
  const unsigned int* psrc = xs + (m & 7) * CPYLEN;
  const int lane_q = h + (m >> 3);
  const int tw0 = w * 256;                     // wave's local t base
  const size_t rowh = ((size_t)b * NFILT + ft * 16 + 4 * h) * T_OUT;

  for (int jp = 0; jp < 8; ++jp) {             // 8 pairs of 16-t tiles
    const int qA = ((tw0 + jp * 32) >> 3) + lane_q;   // chain A base (quad-dwords)
    f32x4 accA = (f32x4){0.f, 0.f, 0.f, 0.f};
    f32x4 accB = (f32x4){0.f, 0.f, 0.f, 0.f};

    #pragma unroll
    for (int c = 0; c < 8; ++c) {
      const bf16x8 xa = *(const bf16x8*)(psrc + 4 * (qA + 4 * c));
      const bf16x8 xb = *(const bf16x8*)(psrc + 4 * (qA + 2 + 4 * c));
      accA = __builtin_amdgcn_mfma_f32_16x16x32_bf16(afr[c], xa, accA, 0, 0, 0);
      accB = __builtin_amdgcn_mfma_f32_16x16x32_bf16(afr[c], xb, accB, 0, 0, 0);
    }

    const int tgA = n0 + tw0 + jp * 32 + m;    // D col = m
    const int tgB = tgA + 16;
    #pragma unroll
    for (int r = 0; r < 4; ++r) {              // D row = 4h + r
      const size_t rb = rowh + (size_t)r * T_OUT;
      if (tgA < T_OUT) __builtin_nontemporal_store(accA[r], &outp[rb + tgA]);
      if (tgB < T_OUT) __builtin_nontemporal_store(accB[r], &outp[rb + tgB]);
    }
  }
}

// ---------------------------------------------------------------------------
extern "C" void kernel_launch(void* const* d_in, const int* in_sizes, int n_in,
                              void* d_out, int out_size, void* d_ws, size_t ws_size,
                              hipStream_t stream) {
  const float* x    = (const float*)d_in[0];
  const float* nf1  = (const float*)d_in[1];
  const float* nf2  = (const float*)d_in[2];
  const float* nf3  = (const float*)d_in[3];
  const float* nf4  = (const float*)d_in[4];
  const float* amp1 = (const float*)d_in[5];
  const float* amp2 = (const float*)d_in[6];
  unsigned short* Wbf = (unsigned short*)d_ws;   // 80*256*2 = 40 KB scratch
  float* out = (float*)d_out;

  build_filters_kernel<<<NFILT, 256, 0, stream>>>(nf1, nf2, nf3, nf4, amp1, amp2, Wbf);

  dim3 grid((T_OUT + NCHUNK - 1) / NCHUNK, NFT, 8);   // 63 x 5 x 8
  conv_mfma_kernel<<<grid, 256, 0, stream>>>(x, Wbf, out);
}

// Round 11
// 58.563 us; speedup vs baseline: 2.6609x; 2.6609x over previous
//
#include <hip/hip_runtime.h>

#define FDIM   251
#define NFILT  80
#define KPAD   256        // K padded to 8 chunks of 32 (zeros past 250)
#define T_IN   64000
#define T_OUT  63750      // 64000 - 251 + 1
#define NCHUNK 1024       // output positions per block; wave owns contiguous 256
#define NFT    5          // filter tiles (16 filters each)
#define CPYLEN 648        // dwords per shifted copy; 648 % 32 == 8 -> bank stagger
#define XSTOT  (8 * CPYLEN)

typedef short bf16x8 __attribute__((ext_vector_type(8)));
typedef float f32x4  __attribute__((ext_vector_type(4)));

__device__ __forceinline__ unsigned short f2bf(float f) {
  unsigned int u = __float_as_uint(f);
  unsigned int r = (u + 0x7fffu + ((u >> 16) & 1u)) >> 16;   // RNE
  return (unsigned short)r;
}
__device__ __forceinline__ unsigned int packbf(float a, float b) {
  return (unsigned int)f2bf(a) | ((unsigned int)f2bf(b) << 16);
}

// ---------------------------------------------------------------------------
// Filter construction (validated rounds 1-10). Emits bf16 W[80][256].
// ---------------------------------------------------------------------------
__device__ __forceinline__ void norm_pm1_shared(float* a, float* scratch, int tid) {
  float v  = (tid < FDIM) ? a[tid] : 0.f;
  float mn = (tid < FDIM) ? v : 1e30f;
  float mx = (tid < FDIM) ? v : -1e30f;
  #pragma unroll
  for (int o = 32; o > 0; o >>= 1) {
    mn = fminf(mn, __shfl_down(mn, o));
    mx = fmaxf(mx, __shfl_down(mx, o));
  }
  const int wid = tid >> 6;
  if ((tid & 63) == 0) { scratch[wid] = mn; scratch[4 + wid] = mx; }
  __syncthreads();
  if (tid == 0) {
    scratch[0] = fminf(fminf(scratch[0], scratch[1]), fminf(scratch[2], scratch[3]));
    scratch[4] = fmaxf(fmaxf(scratch[4], scratch[5]), fmaxf(scratch[6], scratch[7]));
  }
  __syncthreads();
  const float gmn = scratch[0], gmx = scratch[4];
  const float nv = 2.f * (v - gmn) / (gmx - gmn + 1e-6f) - 1.f;
  __syncthreads();
  float s = (tid < FDIM) ? nv : 0.f;
  #pragma unroll
  for (int o = 32; o > 0; o >>= 1) s += __shfl_down(s, o);
  if ((tid & 63) == 0) scratch[wid] = s;
  __syncthreads();
  if (tid == 0) scratch[0] = (scratch[0] + scratch[1] + scratch[2] + scratch[3]) / 251.f;
  __syncthreads();
  const float mean = scratch[0];
  if (tid < FDIM) a[tid] = nv - mean;
  __syncthreads();
}

__global__ __launch_bounds__(256) void build_filters_kernel(
    const float* __restrict__ nf1, const float* __restrict__ nf2,
    const float* __restrict__ nf3, const float* __restrict__ nf4,
    const float* __restrict__ amp1, const float* __restrict__ amp2,
    unsigned short* __restrict__ Wbf) {
  __shared__ float ir1[FDIM], ir2[FDIM], casc[FDIM];
  __shared__ float scratch[8];
  const int f = blockIdx.x, tid = threadIdx.x;
  const float FS  = 16000.f;
  const float MF  = 50.f / 16000.f;
  const float PIF = 3.14159265358979323846f;
  const float TPI = 6.28318530717958647692f;

  const float f1 = fminf(fmaxf(fabsf(nf1[f]) + MF, 0.f), 0.5f);
  const float f2 = fminf(fmaxf(f1 + fabsf(nf2[f] - f1) + MF, 0.f), 0.5f);
  const float f3 = fminf(fmaxf(fabsf(nf3[f]) + MF, 0.f), 0.5f);
  const float f4 = fminf(fmaxf(f3 + fabsf(nf4[f] - f3) + MF, 0.f), 0.5f);
  const float a1 = fabsf(amp1[f]);
  const float a2 = fabsf(amp2[f]);

  if (tid < FDIM) {
    const float t = (float)(tid + 1) / FS;
    {
      const float fcs = 0.5f * (f1 + f2) * FS, bws = (f2 - f1) * FS;
      const float pb = PIF * bws;
      ir1[tid] = a1 * expf(-2.f * pb * pb * (t * t)) * cosf(TPI * fcs * t);
    }
    {
      const float fcs = 0.5f * (f3 + f4) * FS, bws = (f4 - f3) * FS;
      const float pb = PIF * bws;
      ir2[tid] = a2 * expf(-2.f * pb * pb * (t * t)) * cosf(TPI * fcs * t);
    }
  }
  __syncthreads();
  norm_pm1_shared(ir1, scratch, tid);
  norm_pm1_shared(ir2, scratch, tid);

  if (tid < FDIM) {
    const int i = tid;
    const int plo = (i - 125 > 0) ? (i - 125) : 0;
    const int phi = (i + 125 < 250) ? (i + 125) : 250;
    float s = 0.f;
    for (int p = plo; p <= phi; ++p) s += ir1[p] * ir2[p + 125 - i];
    casc[i] = s;
  }
  __syncthreads();
  norm_pm1_shared(casc, scratch, tid);

  if (tid < KPAD) {
    float v = 0.f;
    if (tid < FDIM) {
      const float win = 0.54f - 0.46f * cosf(TPI * ((float)tid / 250.f));
      v = casc[tid] * win;
    }
    Wbf[(size_t)f * KPAD + tid] = f2bf(v);
  }
}

// ---------------------------------------------------------------------------
// Implicit-GEMM conv: round-7 structure + DUAL-PARITY SLIDING RINGS.
// Sliding identity: frag(tile j, chunk c) = G[j+2c] (stride-16 x windows).
// Tiles of one parity share 7/8 fragments. r8 exploited this with ONE ring
// sequentially -> single MFMA chain -> latency stall (75 us, refuted).
// Here BOTH parity rings run concurrently: step tj completes tile 2tj
// (chain A, ring V0) and tile 2tj+1 (chain B, ring V1) with interleaved
// MFMAs; each ring slides by one (2 ds_read_b128 per step).
// LDS reads/wave: 16 init + 14 slide = 30  (r7: 128)  -> LDS pipe ~6 us.
// Same products, same chunk order -> bit-identical output to r2-r10.
// VGPR: V0,V1=64 + afr=32 + acc=8 + addr ~ 112 < 128 cap (256,4); all ring
// indices static via full unroll (r6 spill lesson).
// ---------------------------------------------------------------------------
__global__ __launch_bounds__(256, 4) void conv_mfma_kernel(
    const float* __restrict__ xin, const unsigned short* __restrict__ Wbf,
    float* __restrict__ outp) {
  __shared__ __align__(16) unsigned int xs[XSTOT];
  const int tid = threadIdx.x;
  const int n0  = blockIdx.x * NCHUNK;
  const int ft  = blockIdx.y;
  const int b   = blockIdx.z;
  const int l   = tid & 63, w = tid >> 6;
  const int m   = l & 15, h = l >> 4;

  // ---- stage x as 8 shifted bf16-pair copies: C_j[i] = (x[2i+j], x[2i+j+1]) ----
  const float* xg = xin + (size_t)b * T_IN;
  for (int i = tid; i < CPYLEN - 4; i += 256) {
    float e[10];
    #pragma unroll
    for (int q = 0; q < 10; ++q) {
      const int g = n0 + 2 * i + q;
      e[q] = (g < T_IN) ? xg[g] : 0.f;
    }
    #pragma unroll
    for (int j = 0; j < 8; ++j)
      xs[j * CPYLEN + i] = packbf(e[j], e[j + 1]);
  }

  // ---- W fragments (A-operand) for this 16-filter tile: row = m ----
  const short* Wp = (const short*)Wbf;
  bf16x8 afr[8];
  #pragma unroll
  for (int c = 0; c < 8; ++c)
    afr[c] = *(const bf16x8*)(Wp + (ft * 16 + m) * KPAD + c * 32 + h * 8);

  __syncthreads();

  // lane-constant fragment addressing (validated r4-r10):
  // G[p] -> copy m&7, 16B-unit index qb + 2p, qb = tw0/8 + h + (m>>3).
  // Parity rings: V_p[v] = G[2v+p] at 16B-unit index qb + 4v + 2p.
  const unsigned int* psrc = xs + (m & 7) * CPYLEN;
  const int tw0 = w * 256;
  const int qb = (tw0 >> 3) + h + (m >> 3);
  const size_t rowh = ((size_t)b * NFILT + ft * 16 + 4 * h) * T_OUT;

  bf16x8 V0[8], V1[8];
  #pragma unroll
  for (int s = 0; s < 8; ++s) {
    V0[s] = *(const bf16x8*)(psrc + 4 * (qb + 4 * s));
    V1[s] = *(const bf16x8*)(psrc + 4 * (qb + 4 * s + 2));
  }

  #pragma unroll
  for (int tj = 0; tj < 8; ++tj) {
    f32x4 accA = (f32x4){0.f, 0.f, 0.f, 0.f};
    f32x4 accB = (f32x4){0.f, 0.f, 0.f, 0.f};

    #pragma unroll
    for (int c = 0; c < 8; ++c) {   // two independent chains, interleaved
      accA = __builtin_amdgcn_mfma_f32_16x16x32_bf16(afr[c], V0[(tj + c) & 7], accA, 0, 0, 0);
      accB = __builtin_amdgcn_mfma_f32_16x16x32_bf16(afr[c], V1[(tj + c) & 7], accB, 0, 0, 0);
    }

    const int tgA = n0 + tw0 + tj * 32 + m;    // tile 2tj   (parity 0), D col = m
    const int tgB = tgA + 16;                  // tile 2tj+1 (parity 1)
    #pragma unroll
    for (int r = 0; r < 4; ++r) {              // D row = 4h + r
      const size_t rb = rowh + (size_t)r * T_OUT;
      if (tgA < T_OUT) outp[rb + tgA] = accA[r];
      if (tgB < T_OUT) outp[rb + tgB] = accB[r];
    }

    if (tj < 7) {                              // slide both rings
      V0[tj & 7] = *(const bf16x8*)(psrc + 4 * (qb + 4 * (tj + 8)));
      V1[tj & 7] = *(const bf16x8*)(psrc + 4 * (qb + 4 * (tj + 8) + 2));
    }
  }
}

// ---------------------------------------------------------------------------
extern "C" void kernel_launch(void* const* d_in, const int* in_sizes, int n_in,
                              void* d_out, int out_size, void* d_ws, size_t ws_size,
                              hipStream_t stream) {
  const float* x    = (const float*)d_in[0];
  const float* nf1  = (const float*)d_in[1];
  const float* nf2  = (const float*)d_in[2];
  const float* nf3  = (const float*)d_in[3];
  const float* nf4  = (const float*)d_in[4];
  const float* amp1 = (const float*)d_in[5];
  const float* amp2 = (const float*)d_in[6];
  unsigned short* Wbf = (unsigned short*)d_ws;   // 80*256*2 = 40 KB scratch
  float* out = (float*)d_out;

  build_filters_kernel<<<NFILT, 256, 0, stream>>>(nf1, nf2, nf3, nf4, amp1, amp2, Wbf);

  dim3 grid((T_OUT + NCHUNK - 1) / NCHUNK, NFT, 8);   // 63 x 5 x 8
  conv_mfma_kernel<<<grid, 256, 0, stream>>>(x, Wbf, out);
}